// Round 8
// baseline (173.363 us; speedup 1.0000x reference)
//
#include <hip/hip_runtime.h>

#define N_ 4096
#define C_ 256
#define H_ 16
#define D_ 64
#define HD_ 1024

typedef __attribute__((ext_vector_type(8))) __bf16 bf16x8;
typedef __attribute__((ext_vector_type(4))) __bf16 bf16x4;
typedef __attribute__((ext_vector_type(8))) _Float16 f16x8;
typedef __attribute__((ext_vector_type(4))) _Float16 f16x4;
typedef __attribute__((ext_vector_type(4))) float f32x4;

__device__ __forceinline__ void gload16(const void* g, void* l) {
    __builtin_amdgcn_global_load_lds(
        (const __attribute__((address_space(1))) unsigned int*)g,
        (__attribute__((address_space(3))) unsigned int*)l, 16, 0, 0);
}

struct bf2 { __bf16 h, l; };
__device__ __forceinline__ bf2 split_bf16(float v) {
    bf2 r;
    r.h = (__bf16)v;
    r.l = (__bf16)(v - (float)r.h);
    return r;
}

// ---------------------------------------------------------------------------
// Kernel 0: convert fp32 inputs. X, Wq..Wg -> fp16; Wo -> bf16 hi/lo.
// W transposed K-contiguous. (unchanged from R7)
// ---------------------------------------------------------------------------
__global__ __launch_bounds__(256) void convert_kernel(
    const float* __restrict__ q_x, const float* __restrict__ kv_x,
    const float* __restrict__ Wq, const float* __restrict__ Wk,
    const float* __restrict__ Wv, const float* __restrict__ Wg,
    const float* __restrict__ Wo,
    _Float16* __restrict__ Xf, _Float16* __restrict__ WTf,
    __bf16* __restrict__ WoTh, __bf16* __restrict__ WoTl)
{
    __shared__ float ts[64][65];
    const int b = blockIdx.x;
    const int tid = threadIdx.x;

    if (b < 512) {
        const int seg = b >> 8;
        const float* src = seg ? kv_x : q_x;
        _Float16* df = Xf + (size_t)seg * 1048576;
        const int base = (b & 255) * 4096 + tid * 16;
#pragma unroll
        for (int q = 0; q < 4; ++q) {
            float4 v = *(const float4*)&src[base + q * 4];
            f16x4 fv;
            fv[0] = (_Float16)v.x; fv[1] = (_Float16)v.y;
            fv[2] = (_Float16)v.z; fv[3] = (_Float16)v.w;
            *(f16x4*)&df[base + q * 4] = fv;
        }
        return;
    }

    if (b < 768) {
        const int widx = (b - 512) >> 6;
        const int tile = (b - 512) & 63;
        const float* src = (widx == 0) ? Wq : (widx == 1) ? Wk : (widx == 2) ? Wv : Wg;
        _Float16* df = WTf + (size_t)widx * 262144;
        const int r0 = (tile >> 4) * 64;
        const int c0 = (tile & 15) * 64;
        {
            const int r = tid >> 2;
            const int cch = (tid & 3) * 16;
#pragma unroll
            for (int q = 0; q < 4; ++q) {
                float4 v = *(const float4*)&src[(size_t)(r0 + r) * 1024 + c0 + cch + q * 4];
                ts[r][cch + q * 4 + 0] = v.x;
                ts[r][cch + q * 4 + 1] = v.y;
                ts[r][cch + q * 4 + 2] = v.z;
                ts[r][cch + q * 4 + 3] = v.w;
            }
        }
        __syncthreads();
        {
            const int c = tid >> 2;
            const int rch = (tid & 3) * 16;
#pragma unroll
            for (int q = 0; q < 4; ++q) {
                f16x4 fv;
#pragma unroll
                for (int j = 0; j < 4; ++j)
                    fv[j] = (_Float16)ts[rch + q * 4 + j][c];
                *(f16x4*)&df[(size_t)(c0 + c) * 256 + r0 + rch + q * 4] = fv;
            }
        }
        return;
    }

    {
        const int tile = b - 768;
        const int r0 = (tile >> 2) * 64;
        const int c0 = (tile & 3) * 64;
        {
            const int r = tid >> 2;
            const int cch = (tid & 3) * 16;
#pragma unroll
            for (int q = 0; q < 4; ++q) {
                float4 v = *(const float4*)&Wo[(size_t)(r0 + r) * 256 + c0 + cch + q * 4];
                ts[r][cch + q * 4 + 0] = v.x;
                ts[r][cch + q * 4 + 1] = v.y;
                ts[r][cch + q * 4 + 2] = v.z;
                ts[r][cch + q * 4 + 3] = v.w;
            }
        }
        __syncthreads();
        {
            const int c = tid >> 2;
            const int rch = (tid & 3) * 16;
#pragma unroll
            for (int q = 0; q < 4; ++q) {
                bf16x4 hv, lv;
#pragma unroll
                for (int j = 0; j < 4; ++j) {
                    bf2 s = split_bf16(ts[rch + q * 4 + j][c]);
                    hv[j] = s.h; lv[j] = s.l;
                }
                *(bf16x4*)&WoTh[(size_t)(c0 + c) * 1024 + r0 + rch + q * 4] = hv;
                *(bf16x4*)&WoTl[(size_t)(c0 + c) * 1024 + r0 + rch + q * 4] = lv;
            }
        }
    }
}

// ---------------------------------------------------------------------------
// Kernel 1: projections via fp16 MFMA. 128x128 tile, BK=64, XOR-8 swizzle,
// XCD swizzle. NEW: epilogue routes acc through an LDS fp16 tile [128][136]
// (16B-aligned rows) and stores 8x f16x8 per thread -> full 128-B lines
// per store instruction (was: 64x 2-byte scattered stores/thread, 25%
// write efficiency -> the ~40us plateau of R4/R7).
// ---------------------------------------------------------------------------
__global__ __launch_bounds__(256) void proj_mfma(
    const _Float16* __restrict__ Xf, const _Float16* __restrict__ WTf,
    _Float16* __restrict__ qh, _Float16* __restrict__ kh,
    _Float16* __restrict__ vh, _Float16* __restrict__ gh)
{
    __shared__ __align__(16) char psmem[34816];   // max(2x16KB staging, 128x136 fp16 epi)
    _Float16* As = (_Float16*)psmem;
    _Float16* Bs = (_Float16*)(psmem + 16384);

    const int lb  = blockIdx.x;
    const int xcd = lb & 7;
    const int gr  = (lb >> 6) * 8 + xcd;    // 0..127 -> (g, row-tile)
    const int g   = gr >> 5;
    const int m0  = (gr & 31) * 128;
    const int c0  = ((lb >> 3) & 7) * 128;

    const _Float16* A = Xf + ((g == 1 || g == 2) ? 1048576 : 0);
    const _Float16* B = WTf + (size_t)g * 262144;

    const int tid  = threadIdx.x;
    const int wave = tid >> 6;
    const int lane = tid & 63;
    const int wr   = wave >> 1;
    const int wc   = wave & 1;
    const int frow = lane & 15;
    const int grp  = lane >> 4;

    f32x4 acc[4][4];
#pragma unroll
    for (int i = 0; i < 4; ++i)
#pragma unroll
        for (int j = 0; j < 4; ++j) acc[i][j] = (f32x4){0.f, 0.f, 0.f, 0.f};

    const int srow = tid >> 3;              // 0..31
    const int sch  = tid & 7;               // chunk 0..7

    for (int kt = 0; kt < 256; kt += 64) {
        __syncthreads();
#pragma unroll
        for (int p = 0; p < 4; ++p) {
            const int row = p * 32 + srow;
            const int koff = kt + ((sch ^ (row & 7)) << 3);
            gload16(A + (size_t)(m0 + row) * 256 + koff, (char*)As + p * 4096 + tid * 16);
            gload16(B + (size_t)(c0 + row) * 256 + koff, (char*)Bs + p * 4096 + tid * 16);
        }
        __syncthreads();

#pragma unroll
        for (int ks = 0; ks < 2; ++ks) {
            f16x8 af[4], bf[4];
#pragma unroll
            for (int f = 0; f < 4; ++f) {
                const int ra = wr * 64 + f * 16 + frow;
                const int rb = wc * 64 + f * 16 + frow;
                af[f] = *(const f16x8*)((char*)As + ra * 128 + (((ks * 4 + grp) ^ (ra & 7)) << 4));
                bf[f] = *(const f16x8*)((char*)Bs + rb * 128 + (((ks * 4 + grp) ^ (rb & 7)) << 4));
            }
#pragma unroll
            for (int i = 0; i < 4; ++i)
#pragma unroll
                for (int j = 0; j < 4; ++j)
                    acc[i][j] = __builtin_amdgcn_mfma_f32_16x16x32_f16(af[i], bf[j], acc[i][j], 0, 0, 0);
        }
    }

    // ---- epilogue: acc -> LDS fp16 [128][136] -> vectorized 16B stores ----
    __syncthreads();                         // all LDS frag reads done
    _Float16* Epi = (_Float16*)psmem;
    {
        const float scale = (g == 0) ? 0.125f : 1.f;
#pragma unroll
        for (int i = 0; i < 4; ++i)
#pragma unroll
            for (int j = 0; j < 4; ++j) {
                const int rr = wr * 64 + i * 16 + grp * 4;
                const int cc = wc * 64 + j * 16 + frow;
#pragma unroll
                for (int v = 0; v < 4; ++v) {
                    float x = acc[i][j][v];
                    x = (g == 3) ? 1.f / (1.f + __expf(-x)) : x * scale;
                    Epi[(rr + v) * 136 + cc] = (_Float16)x;
                }
            }
    }
    __syncthreads();
    {
        const int ch   = tid & 15;           // 16 chunks per tile-row
        const int head = ch >> 3;            // col half 0/1
        const int e8   = (ch & 7) * 8;       // 16B chunk within head-row
#pragma unroll
        for (int p = 0; p < 8; ++p) {
            const int r = p * 16 + (tid >> 4);
            const f16x8 val = *(const f16x8*)&Epi[r * 136 + head * 64 + e8];
            if (g == 3) {
                *(f16x8*)&gh[(size_t)(m0 + r) * HD_ + c0 + head * 64 + e8] = val;
            } else {
                _Float16* dst = (g == 0) ? qh : (g == 1) ? kh : vh;
                const int hh = (c0 >> 6) + head;
                *(f16x8*)&dst[((size_t)hh * N_ + m0 + r) * D_ + e8] = val;
            }
        }
    }
}

// ---------------------------------------------------------------------------
// Kernel 2: local attention via fp16 MFMA. One block per (h,t), 4 waves.
// XCD swizzle. NEW: epilogue stages O*inv in LDS fp32 [64][68] (overlays Ps)
// and stores 4x 16B bf16x8 per thread (was 32 scalar 2B stores).
// ---------------------------------------------------------------------------
__global__ __launch_bounds__(256) void attn_mfma(
    const _Float16* __restrict__ qh, const _Float16* __restrict__ kh,
    const _Float16* __restrict__ vh, const float* __restrict__ bias,
    const _Float16* __restrict__ gh,
    __bf16* __restrict__ o_hi, __bf16* __restrict__ o_lo)
{
    __shared__ __align__(16) char smem[59392];
    _Float16* Qs = (_Float16*)smem;              // [64][64], swizzled chunks, 8 KB
    char* Ks = smem + 8192;                      // K: [128][64] swizzled, 16 KB
    _Float16* Vs = (_Float16*)(smem + 8192);     // V^T: [64][136] (overlays Ks)
    _Float16* Ps = (_Float16*)(smem + 25600);    // [64][264], 33792 B
    float* Oe = (float*)(smem + 25600);          // [64][68] fp32 epi (overlays Ps)

    const int lb  = blockIdx.x;
    const int xcd = lb & 7;
    const int j_  = lb >> 3;
    const int h   = j_ >> 3;
    const int t   = xcd * 8 + (j_ & 7);
    const int tid = threadIdx.x;
    const int lane = tid & 63;
    const int wv = tid >> 6;
    const int frow = lane & 15;
    const int grp = lane >> 4;
    const int kbase = t * 64 - 96;

    const char* qbase = (const char*)qh + (size_t)(h * N_ + t * 64) * 128;
    const char* kbase_p = (const char*)kh + (size_t)h * N_ * 128;

#pragma unroll
    for (int q = 0; q < 2; ++q) {
        const int lin = q * 4096 + tid * 16;
        const int row = lin >> 7;
        const int ch = (lin >> 4) & 7;
        gload16(qbase + row * 128 + ((ch ^ (row & 7)) << 4), (char*)Qs + lin);
    }

    f32x4 sacc[16];

#pragma unroll
    for (int p = 0; p < 2; ++p) {
#pragma unroll
        for (int q = 0; q < 4; ++q) {
            const int lin = q * 4096 + tid * 16;
            const int row = lin >> 7;
            const int ch = (lin >> 4) & 7;
            const int kg = kbase + p * 128 + row;
            if ((unsigned)kg < (unsigned)N_) {
                gload16(kbase_p + (size_t)kg * 128 + ((ch ^ (row & 7)) << 4), Ks + lin);
            } else {
                *(float4*)(Ks + lin) = make_float4(0.f, 0.f, 0.f, 0.f);
            }
        }
        {
            const int rowg = t * 64 + wv * 16 + grp * 4;
#pragma unroll
            for (int j = 0; j < 8; ++j) {
                const int colg = kbase + p * 128 + j * 16 + frow;
                const bool ok = (unsigned)colg < (unsigned)N_;
#pragma unroll
                for (int v = 0; v < 4; ++v)
                    sacc[p * 8 + j][v] = ok ? bias[(size_t)(rowg + v) * N_ + colg] : 0.f;
            }
        }
        __syncthreads();
        const int rq = wv * 16 + frow;
#pragma unroll
        for (int ks = 0; ks < 2; ++ks) {
            const f16x8 aq = *(const f16x8*)((char*)Qs + rq * 128 + (((ks * 4 + grp) ^ (rq & 7)) << 4));
#pragma unroll
            for (int j = 0; j < 8; ++j) {
                const int rk = j * 16 + frow;
                const f16x8 bk = *(const f16x8*)(Ks + rk * 128 + (((ks * 4 + grp) ^ (rk & 7)) << 4));
                sacc[p * 8 + j] = __builtin_amdgcn_mfma_f32_16x16x32_f16(aq, bk, sacc[p * 8 + j], 0, 0, 0);
            }
        }
        __syncthreads();
    }

    float inv[4];
#pragma unroll
    for (int v = 0; v < 4; ++v) {
        float m = sacc[0][v];
#pragma unroll
        for (int f = 1; f < 16; ++f) m = fmaxf(m, sacc[f][v]);
        m = fmaxf(m, __shfl_xor(m, 1));
        m = fmaxf(m, __shfl_xor(m, 2));
        m = fmaxf(m, __shfl_xor(m, 4));
        m = fmaxf(m, __shfl_xor(m, 8));
        float l = 0.f;
#pragma unroll
        for (int f = 0; f < 16; ++f) {
            float e = __expf(sacc[f][v] - m);
            sacc[f][v] = e;
            l += e;
        }
        l += __shfl_xor(l, 1);
        l += __shfl_xor(l, 2);
        l += __shfl_xor(l, 4);
        l += __shfl_xor(l, 8);
        inv[v] = 1.f / l;
    }

    {
        const int rb = wv * 16 + grp * 4;
#pragma unroll
        for (int f = 0; f < 16; ++f) {
            const int col = (f >> 3) * 128 + (f & 7) * 16 + frow;
#pragma unroll
            for (int v = 0; v < 4; ++v)
                Ps[(rb + v) * 264 + col] = (_Float16)sacc[f][v];
        }
    }

    f32x4 oacc[4];
#pragma unroll
    for (int jd = 0; jd < 4; ++jd) oacc[jd] = (f32x4){0.f, 0.f, 0.f, 0.f};

#pragma unroll
    for (int c = 0; c < 2; ++c) {
        {
            const int sl = tid >> 1;
            const int d0 = (tid & 1) * 32;
            const int kg = kbase + c * 128 + sl;
            f16x8 vv[4];
            if ((unsigned)kg < (unsigned)N_) {
                const f16x8* vp = (const f16x8*)(vh + ((size_t)h * N_ + kg) * D_ + d0);
#pragma unroll
                for (int q = 0; q < 4; ++q) vv[q] = vp[q];
            } else {
#pragma unroll
                for (int q = 0; q < 4; ++q)
#pragma unroll
                    for (int e = 0; e < 8; ++e) vv[q][e] = (_Float16)0.f;
            }
#pragma unroll
            for (int q = 0; q < 4; ++q)
#pragma unroll
                for (int e = 0; e < 8; ++e)
                    Vs[(d0 + q * 8 + e) * 136 + sl] = vv[q][e];
        }
        __syncthreads();
        const int rp = wv * 16 + frow;
#pragma unroll
        for (int ks = 0; ks < 4; ++ks) {
            const f16x8 ap = *(const f16x8*)((char*)Ps + rp * 528 + c * 256 + ks * 64 + grp * 16);
#pragma unroll
            for (int jd = 0; jd < 4; ++jd) {
                const f16x8 bv = *(const f16x8*)((char*)Vs + (jd * 16 + frow) * 272 + ks * 64 + grp * 16);
                oacc[jd] = __builtin_amdgcn_mfma_f32_16x16x32_f16(ap, bv, oacc[jd], 0, 0, 0);
            }
        }
        __syncthreads();
    }

    // ---- epilogue: O*inv -> LDS fp32 [64][68]; readback * gate -> 16B stores
#pragma unroll
    for (int jd = 0; jd < 4; ++jd) {
        const int dcol = jd * 16 + frow;
#pragma unroll
        for (int v = 0; v < 4; ++v) {
            const int rn = wv * 16 + grp * 4 + v;
            Oe[rn * 68 + dcol] = oacc[jd][v] * inv[v];
        }
    }
    __syncthreads();
    {
        const int r   = tid >> 2;            // 0..63
        const int seg = tid & 3;             // 16-col segment
        const int n   = t * 64 + r;
        const int cg0 = h * 64 + seg * 16;
        const float* orow = &Oe[r * 68 + seg * 16];
        f32x4 o0 = *(const f32x4*)&orow[0];
        f32x4 o1 = *(const f32x4*)&orow[4];
        f32x4 o2 = *(const f32x4*)&orow[8];
        f32x4 o3 = *(const f32x4*)&orow[12];
        const f16x8 g0 = *(const f16x8*)&gh[(size_t)n * HD_ + cg0];
        const f16x8 g1 = *(const f16x8*)&gh[(size_t)n * HD_ + cg0 + 8];
        float vals[16];
#pragma unroll
        for (int e = 0; e < 4; ++e) {
            vals[e]      = o0[e] * (float)g0[e];
            vals[4 + e]  = o1[e] * (float)g0[4 + e];
            vals[8 + e]  = o2[e] * (float)g1[e];
            vals[12 + e] = o3[e] * (float)g1[4 + e];
        }
        bf16x8 hi0, hi1, lo0, lo1;
#pragma unroll
        for (int e = 0; e < 8; ++e) {
            bf2 s0 = split_bf16(vals[e]);
            bf2 s1 = split_bf16(vals[8 + e]);
            hi0[e] = s0.h; lo0[e] = s0.l;
            hi1[e] = s1.h; lo1[e] = s1.l;
        }
        *(bf16x8*)&o_hi[(size_t)n * HD_ + cg0]     = hi0;
        *(bf16x8*)&o_hi[(size_t)n * HD_ + cg0 + 8] = hi1;
        *(bf16x8*)&o_lo[(size_t)n * HD_ + cg0]     = lo0;
        *(bf16x8*)&o_lo[(size_t)n * HD_ + cg0 + 8] = lo1;
    }
}

// ---------------------------------------------------------------------------
// Kernel 3: out = (o*g)[4096x1024] @ Wo[1024x256] via split-bf16 MFMA.
// Tile 64x64, XCD swizzle. NEW: BK=64 (16 iters, half the barrier drains)
// + XOR-8 chunk swizzle (conflict-free b128 frag reads).
// ---------------------------------------------------------------------------
__global__ __launch_bounds__(256) void out_mfma(
    const __bf16* __restrict__ o_hi, const __bf16* __restrict__ o_lo,
    const __bf16* __restrict__ WoTh, const __bf16* __restrict__ WoTl,
    float* __restrict__ out)
{
    __shared__ __align__(16) __bf16 smem[4 * 4096];  // 8KB each: As_h, As_l, Bs_h, Bs_l
    __bf16* As_h = smem;
    __bf16* As_l = smem + 4096;
    __bf16* Bs_h = smem + 8192;
    __bf16* Bs_l = smem + 12288;

    const int lb  = blockIdx.x;
    const int xcd = lb & 7;
    const int idx = lb >> 3;                 // 0..31
    const int rowg = (idx >> 2) * 8 + xcd;   // 0..63
    const int m0  = rowg * 64;
    const int c0  = (idx & 3) * 64;

    const int tid  = threadIdx.x;
    const int wave = tid >> 6;
    const int lane = tid & 63;
    const int wr   = wave >> 1;
    const int wc   = wave & 1;
    const int frow = lane & 15;
    const int grp  = lane >> 4;

    f32x4 acc[2][2];
#pragma unroll
    for (int i = 0; i < 2; ++i)
#pragma unroll
        for (int j = 0; j < 2; ++j) acc[i][j] = (f32x4){0.f, 0.f, 0.f, 0.f};

    for (int kt = 0; kt < 1024; kt += 64) {
        __syncthreads();
#pragma unroll
        for (int p = 0; p < 2; ++p) {
            const int lin = p * 4096 + tid * 16;
            const int row = lin >> 7;            // 0..63
            const int ch  = (lin >> 4) & 7;
            const int koff = kt + ((ch ^ (row & 7)) << 3);
            gload16(o_hi + (size_t)(m0 + row) * HD_ + koff, (char*)As_h + lin);
            gload16(o_lo + (size_t)(m0 + row) * HD_ + koff, (char*)As_l + lin);
            gload16(WoTh + (size_t)(c0 + row) * HD_ + koff, (char*)Bs_h + lin);
            gload16(WoTl + (size_t)(c0 + row) * HD_ + koff, (char*)Bs_l + lin);
        }
        __syncthreads();

#pragma unroll
        for (int ks = 0; ks < 2; ++ks) {
            bf16x8 afh[2], afl[2], bfh[2], bfl[2];
#pragma unroll
            for (int f = 0; f < 2; ++f) {
                const int ra = wr * 32 + f * 16 + frow;
                const int rb = wc * 32 + f * 16 + frow;
                const int ca = ((ks * 4 + grp) ^ (ra & 7)) << 4;
                const int cb = ((ks * 4 + grp) ^ (rb & 7)) << 4;
                afh[f] = *(const bf16x8*)((char*)As_h + ra * 128 + ca);
                afl[f] = *(const bf16x8*)((char*)As_l + ra * 128 + ca);
                bfh[f] = *(const bf16x8*)((char*)Bs_h + rb * 128 + cb);
                bfl[f] = *(const bf16x8*)((char*)Bs_l + rb * 128 + cb);
            }
#pragma unroll
            for (int i = 0; i < 2; ++i)
#pragma unroll
                for (int j = 0; j < 2; ++j) {
                    acc[i][j] = __builtin_amdgcn_mfma_f32_16x16x32_bf16(afh[i], bfh[j], acc[i][j], 0, 0, 0);
                    acc[i][j] = __builtin_amdgcn_mfma_f32_16x16x32_bf16(afl[i], bfh[j], acc[i][j], 0, 0, 0);
                    acc[i][j] = __builtin_amdgcn_mfma_f32_16x16x32_bf16(afh[i], bfl[j], acc[i][j], 0, 0, 0);
                }
        }
    }

    const int rbase = grp * 4;
#pragma unroll
    for (int i = 0; i < 2; ++i)
#pragma unroll
        for (int j = 0; j < 2; ++j) {
            const int c = c0 + wc * 32 + j * 16 + frow;
#pragma unroll
            for (int v = 0; v < 4; ++v) {
                const int n = m0 + wr * 32 + i * 16 + rbase + v;
                out[(size_t)n * C_ + c] = acc[i][j][v];
            }
        }
}

// ---------------------------------------------------------------------------
extern "C" void kernel_launch(void* const* d_in, const int* in_sizes, int n_in,
                              void* d_out, int out_size, void* d_ws, size_t ws_size,
                              hipStream_t stream)
{
    const float* q_x  = (const float*)d_in[0];
    const float* kv_x = (const float*)d_in[1];
    const float* bias = (const float*)d_in[2];
    const float* Wq   = (const float*)d_in[3];
    const float* Wk   = (const float*)d_in[4];
    const float* Wv   = (const float*)d_in[5];
    const float* Wg   = (const float*)d_in[6];
    const float* Wo   = (const float*)d_in[7];
    float* out = (float*)d_out;

    char* ws = (char*)d_ws;
    const size_t MB = 1048576;
    _Float16* qh  = (_Float16*)(ws);             // [16][4096][64] fp16, pre-scaled 1/8
    _Float16* kh  = (_Float16*)(ws + 8  * MB);
    _Float16* vh  = (_Float16*)(ws + 16 * MB);
    _Float16* gh  = (_Float16*)(ws + 24 * MB);   // [4096][1024] fp16 sigmoid gate
    __bf16* o_hi  = (__bf16*)(ws + 32 * MB);     // [4096][1024] bf16
    __bf16* o_lo  = (__bf16*)(ws + 40 * MB);
    _Float16* Xf  = (_Float16*)(ws + 48 * MB);   // [2][4096][256] fp16
    _Float16* WTf = (_Float16*)(ws + 52 * MB);   // [4][1024][256] fp16
    __bf16* WoTh  = (__bf16*)(ws + 54 * MB);     // [256][1024]
    __bf16* WoTl  = (__bf16*)(ws + 54 * MB + 524288);

    convert_kernel<<<832, 256, 0, stream>>>(q_x, kv_x, Wq, Wk, Wv, Wg, Wo,
                                            Xf, WTf, WoTh, WoTl);
    proj_mfma<<<1024, 256, 0, stream>>>(Xf, WTf, qh, kh, vh, gh);
    attn_mfma<<<1024, 256, 0, stream>>>(qh, kh, vh, bias, gh, o_hi, o_lo);
    out_mfma<<<256, 256, 0, stream>>>(o_hi, o_lo, WoTh, WoTl, out);
}

// Round 9
// 163.658 us; speedup vs baseline: 1.0593x; 1.0593x over previous
//
#include <hip/hip_runtime.h>

#define N_ 4096
#define C_ 256
#define H_ 16
#define D_ 64
#define HD_ 1024

typedef __attribute__((ext_vector_type(8))) __bf16 bf16x8;
typedef __attribute__((ext_vector_type(8))) _Float16 f16x8;
typedef __attribute__((ext_vector_type(4))) _Float16 f16x4;
typedef __attribute__((ext_vector_type(4))) float f32x4;

__device__ __forceinline__ void gload16(const void* g, void* l) {
    __builtin_amdgcn_global_load_lds(
        (const __attribute__((address_space(1))) unsigned int*)g,
        (__attribute__((address_space(3))) unsigned int*)l, 16, 0, 0);
}

// ---------------------------------------------------------------------------
// Kernel 0: convert fp32 inputs -> fp16 (X, Wq..Wg, Wo). W transposed
// K-contiguous. All-fp16 pipeline now (out GEMM no longer split-bf16).
// ---------------------------------------------------------------------------
__global__ __launch_bounds__(256) void convert_kernel(
    const float* __restrict__ q_x, const float* __restrict__ kv_x,
    const float* __restrict__ Wq, const float* __restrict__ Wk,
    const float* __restrict__ Wv, const float* __restrict__ Wg,
    const float* __restrict__ Wo,
    _Float16* __restrict__ Xf, _Float16* __restrict__ WTf,
    _Float16* __restrict__ WoTf)
{
    __shared__ float ts[64][65];
    const int b = blockIdx.x;
    const int tid = threadIdx.x;

    if (b < 512) {
        const int seg = b >> 8;
        const float* src = seg ? kv_x : q_x;
        _Float16* df = Xf + (size_t)seg * 1048576;
        const int base = (b & 255) * 4096 + tid * 16;
#pragma unroll
        for (int q = 0; q < 4; ++q) {
            float4 v = *(const float4*)&src[base + q * 4];
            f16x4 fv;
            fv[0] = (_Float16)v.x; fv[1] = (_Float16)v.y;
            fv[2] = (_Float16)v.z; fv[3] = (_Float16)v.w;
            *(f16x4*)&df[base + q * 4] = fv;
        }
        return;
    }

    // transpose path
    const float* src;
    _Float16* df;
    int srcC, dstC, r0, c0;
    if (b < 768) {
        const int widx = (b - 512) >> 6;
        const int tile = (b - 512) & 63;
        src = (widx == 0) ? Wq : (widx == 1) ? Wk : (widx == 2) ? Wv : Wg;
        df = WTf + (size_t)widx * 262144;
        srcC = 1024; dstC = 256;
        r0 = (tile >> 4) * 64;
        c0 = (tile & 15) * 64;
    } else {
        const int tile = b - 768;
        src = Wo; df = WoTf;
        srcC = 256; dstC = 1024;
        r0 = (tile >> 2) * 64;
        c0 = (tile & 3) * 64;
    }
    {
        const int r = tid >> 2;
        const int cch = (tid & 3) * 16;
#pragma unroll
        for (int q = 0; q < 4; ++q) {
            float4 v = *(const float4*)&src[(size_t)(r0 + r) * srcC + c0 + cch + q * 4];
            ts[r][cch + q * 4 + 0] = v.x;
            ts[r][cch + q * 4 + 1] = v.y;
            ts[r][cch + q * 4 + 2] = v.z;
            ts[r][cch + q * 4 + 3] = v.w;
        }
    }
    __syncthreads();
    {
        const int c = tid >> 2;
        const int rch = (tid & 3) * 16;
#pragma unroll
        for (int q = 0; q < 4; ++q) {
            f16x4 fv;
#pragma unroll
            for (int j = 0; j < 4; ++j)
                fv[j] = (_Float16)ts[rch + q * 4 + j][c];
            *(f16x4*)&df[(size_t)(c0 + c) * dstC + r0 + rch + q * 4] = fv;
        }
    }
}

// ---------------------------------------------------------------------------
// Kernel 1: projections via fp16 MFMA. 128x128 tile, BK=64, XOR-8 swizzle,
// XCD swizzle, LDS-routed vectorized epilogue. (unchanged from R8)
// ---------------------------------------------------------------------------
__global__ __launch_bounds__(256) void proj_mfma(
    const _Float16* __restrict__ Xf, const _Float16* __restrict__ WTf,
    _Float16* __restrict__ qh, _Float16* __restrict__ kh,
    _Float16* __restrict__ vh, _Float16* __restrict__ gh)
{
    __shared__ __align__(16) char psmem[34816];
    _Float16* As = (_Float16*)psmem;
    _Float16* Bs = (_Float16*)(psmem + 16384);

    const int lb  = blockIdx.x;
    const int xcd = lb & 7;
    const int gr  = (lb >> 6) * 8 + xcd;    // 0..127 -> (g, row-tile)
    const int g   = gr >> 5;
    const int m0  = (gr & 31) * 128;
    const int c0  = ((lb >> 3) & 7) * 128;

    const _Float16* A = Xf + ((g == 1 || g == 2) ? 1048576 : 0);
    const _Float16* B = WTf + (size_t)g * 262144;

    const int tid  = threadIdx.x;
    const int wave = tid >> 6;
    const int lane = tid & 63;
    const int wr   = wave >> 1;
    const int wc   = wave & 1;
    const int frow = lane & 15;
    const int grp  = lane >> 4;

    f32x4 acc[4][4];
#pragma unroll
    for (int i = 0; i < 4; ++i)
#pragma unroll
        for (int j = 0; j < 4; ++j) acc[i][j] = (f32x4){0.f, 0.f, 0.f, 0.f};

    const int srow = tid >> 3;
    const int sch  = tid & 7;

    for (int kt = 0; kt < 256; kt += 64) {
        __syncthreads();
#pragma unroll
        for (int p = 0; p < 4; ++p) {
            const int row = p * 32 + srow;
            const int koff = kt + ((sch ^ (row & 7)) << 3);
            gload16(A + (size_t)(m0 + row) * 256 + koff, (char*)As + p * 4096 + tid * 16);
            gload16(B + (size_t)(c0 + row) * 256 + koff, (char*)Bs + p * 4096 + tid * 16);
        }
        __syncthreads();

#pragma unroll
        for (int ks = 0; ks < 2; ++ks) {
            f16x8 af[4], bf[4];
#pragma unroll
            for (int f = 0; f < 4; ++f) {
                const int ra = wr * 64 + f * 16 + frow;
                const int rb = wc * 64 + f * 16 + frow;
                af[f] = *(const f16x8*)((char*)As + ra * 128 + (((ks * 4 + grp) ^ (ra & 7)) << 4));
                bf[f] = *(const f16x8*)((char*)Bs + rb * 128 + (((ks * 4 + grp) ^ (rb & 7)) << 4));
            }
#pragma unroll
            for (int i = 0; i < 4; ++i)
#pragma unroll
                for (int j = 0; j < 4; ++j)
                    acc[i][j] = __builtin_amdgcn_mfma_f32_16x16x32_f16(af[i], bf[j], acc[i][j], 0, 0, 0);
        }
    }

    __syncthreads();
    _Float16* Epi = (_Float16*)psmem;        // [128][136] fp16
    {
        const float scale = (g == 0) ? 0.125f : 1.f;
#pragma unroll
        for (int i = 0; i < 4; ++i)
#pragma unroll
            for (int j = 0; j < 4; ++j) {
                const int rr = wr * 64 + i * 16 + grp * 4;
                const int cc = wc * 64 + j * 16 + frow;
#pragma unroll
                for (int v = 0; v < 4; ++v) {
                    float x = acc[i][j][v];
                    x = (g == 3) ? 1.f / (1.f + __expf(-x)) : x * scale;
                    Epi[(rr + v) * 136 + cc] = (_Float16)x;
                }
            }
    }
    __syncthreads();
    {
        const int ch   = tid & 15;
        const int head = ch >> 3;
        const int e8   = (ch & 7) * 8;
#pragma unroll
        for (int p = 0; p < 8; ++p) {
            const int r = p * 16 + (tid >> 4);
            const f16x8 val = *(const f16x8*)&Epi[r * 136 + head * 64 + e8];
            if (g == 3) {
                *(f16x8*)&gh[(size_t)(m0 + r) * HD_ + c0 + head * 64 + e8] = val;
            } else {
                _Float16* dst = (g == 0) ? qh : (g == 1) ? kh : vh;
                const int hh = (c0 >> 6) + head;
                *(f16x8*)&dst[((size_t)hh * N_ + m0 + r) * D_ + e8] = val;
            }
        }
    }
}

// ---------------------------------------------------------------------------
// Kernel 2: local attention via fp16 MFMA. One block per (h,t), 4 waves.
// XCD swizzle. NEW (R9): LDS cut 59.4 -> 34.8 KB so 4 blocks/CU (was 2):
// P is written per-128-slot chunk inside the PV loop (values live in sacc),
// overlaid on the dead Qs/Ks regions. __launch_bounds__(256,4) pins VGPR.
// Output o now single fp16 (out GEMM is plain fp16).
// ---------------------------------------------------------------------------
__global__ __launch_bounds__(256, 4) void attn_mfma(
    const _Float16* __restrict__ qh, const _Float16* __restrict__ kh,
    const _Float16* __restrict__ vh, const float* __restrict__ bias,
    const _Float16* __restrict__ gh, _Float16* __restrict__ of)
{
    __shared__ __align__(16) char smem[34816];
    _Float16* Qs = (_Float16*)smem;              // phase A: [64][64] swz, 8 KB
    char* Ks = smem + 8192;                      // phase A: [128][64] swz, 16 KB
    _Float16* Ps = (_Float16*)smem;              // phase B: [64][136], 17408 B
    _Float16* Vs = (_Float16*)(smem + 17408);    // phase B: [64][136], 17408 B
    float* Oe = (float*)smem;                    // epi: [64][68] fp32, 17408 B

    const int lb  = blockIdx.x;
    const int xcd = lb & 7;
    const int j_  = lb >> 3;
    const int h   = j_ >> 3;
    const int t   = xcd * 8 + (j_ & 7);
    const int tid = threadIdx.x;
    const int lane = tid & 63;
    const int wv = tid >> 6;
    const int frow = lane & 15;
    const int grp = lane >> 4;
    const int kbase = t * 64 - 96;

    const char* qbase = (const char*)qh + (size_t)(h * N_ + t * 64) * 128;
    const char* kbase_p = (const char*)kh + (size_t)h * N_ * 128;

    // ---- stage Q (8 KB), async ----
#pragma unroll
    for (int q = 0; q < 2; ++q) {
        const int lin = q * 4096 + tid * 16;
        const int row = lin >> 7;
        const int ch = (lin >> 4) & 7;
        gload16(qbase + row * 128 + ((ch ^ (row & 7)) << 4), (char*)Qs + lin);
    }

    f32x4 sacc[16];

#pragma unroll
    for (int p = 0; p < 2; ++p) {
#pragma unroll
        for (int q = 0; q < 4; ++q) {
            const int lin = q * 4096 + tid * 16;
            const int row = lin >> 7;
            const int ch = (lin >> 4) & 7;
            const int kg = kbase + p * 128 + row;
            if ((unsigned)kg < (unsigned)N_) {
                gload16(kbase_p + (size_t)kg * 128 + ((ch ^ (row & 7)) << 4), Ks + lin);
            } else {
                *(float4*)(Ks + lin) = make_float4(0.f, 0.f, 0.f, 0.f);
            }
        }
        {
            const int rowg = t * 64 + wv * 16 + grp * 4;
#pragma unroll
            for (int j = 0; j < 8; ++j) {
                const int colg = kbase + p * 128 + j * 16 + frow;
                const bool ok = (unsigned)colg < (unsigned)N_;
#pragma unroll
                for (int v = 0; v < 4; ++v)
                    sacc[p * 8 + j][v] = ok ? bias[(size_t)(rowg + v) * N_ + colg] : 0.f;
            }
        }
        __syncthreads();
        const int rq = wv * 16 + frow;
#pragma unroll
        for (int ks = 0; ks < 2; ++ks) {
            const f16x8 aq = *(const f16x8*)((char*)Qs + rq * 128 + (((ks * 4 + grp) ^ (rq & 7)) << 4));
#pragma unroll
            for (int j = 0; j < 8; ++j) {
                const int rk = j * 16 + frow;
                const f16x8 bk = *(const f16x8*)(Ks + rk * 128 + (((ks * 4 + grp) ^ (rk & 7)) << 4));
                sacc[p * 8 + j] = __builtin_amdgcn_mfma_f32_16x16x32_f16(aq, bk, sacc[p * 8 + j], 0, 0, 0);
            }
        }
        __syncthreads();   // K/Q reads done before restage / phase-B overlay
    }

    // ---- softmax over 256 slots/row ----
    float inv[4];
#pragma unroll
    for (int v = 0; v < 4; ++v) {
        float m = sacc[0][v];
#pragma unroll
        for (int f = 1; f < 16; ++f) m = fmaxf(m, sacc[f][v]);
        m = fmaxf(m, __shfl_xor(m, 1));
        m = fmaxf(m, __shfl_xor(m, 2));
        m = fmaxf(m, __shfl_xor(m, 4));
        m = fmaxf(m, __shfl_xor(m, 8));
        float l = 0.f;
#pragma unroll
        for (int f = 0; f < 16; ++f) {
            float e = __expf(sacc[f][v] - m);
            sacc[f][v] = e;
            l += e;
        }
        l += __shfl_xor(l, 1);
        l += __shfl_xor(l, 2);
        l += __shfl_xor(l, 4);
        l += __shfl_xor(l, 8);
        inv[v] = 1.f / l;
    }

    // ---- PV over 2 slot-chunks; P written per-chunk from sacc ----
    f32x4 oacc[4];
#pragma unroll
    for (int jd = 0; jd < 4; ++jd) oacc[jd] = (f32x4){0.f, 0.f, 0.f, 0.f};

#pragma unroll
    for (int c = 0; c < 2; ++c) {
        // stage V^T chunk: Vs[d][sl], sl 0..127
        {
            const int sl = tid >> 1;
            const int d0 = (tid & 1) * 32;
            const int kg = kbase + c * 128 + sl;
            f16x8 vv[4];
            if ((unsigned)kg < (unsigned)N_) {
                const f16x8* vp = (const f16x8*)(vh + ((size_t)h * N_ + kg) * D_ + d0);
#pragma unroll
                for (int q = 0; q < 4; ++q) vv[q] = vp[q];
            } else {
#pragma unroll
                for (int q = 0; q < 4; ++q)
#pragma unroll
                    for (int e = 0; e < 8; ++e) vv[q][e] = (_Float16)0.f;
            }
#pragma unroll
            for (int q = 0; q < 4; ++q)
#pragma unroll
                for (int e = 0; e < 8; ++e)
                    Vs[(d0 + q * 8 + e) * 136 + sl] = vv[q][e];
        }
        // write this chunk's unnormalized P: Ps[row][slot-in-chunk]
        {
            const int rb = wv * 16 + grp * 4;
#pragma unroll
            for (int j = 0; j < 8; ++j) {
                const int col = j * 16 + frow;
#pragma unroll
                for (int v = 0; v < 4; ++v)
                    Ps[(rb + v) * 136 + col] = (_Float16)sacc[c * 8 + j][v];
            }
        }
        __syncthreads();   // Ps + Vs ready
        const int rp = wv * 16 + frow;
#pragma unroll
        for (int ks = 0; ks < 4; ++ks) {
            const f16x8 ap = *(const f16x8*)((char*)Ps + rp * 272 + ks * 64 + grp * 16);
#pragma unroll
            for (int jd = 0; jd < 4; ++jd) {
                const f16x8 bv = *(const f16x8*)((char*)Vs + (jd * 16 + frow) * 272 + ks * 64 + grp * 16);
                oacc[jd] = __builtin_amdgcn_mfma_f32_16x16x32_f16(ap, bv, oacc[jd], 0, 0, 0);
            }
        }
        __syncthreads();   // Ps/Vs reads done before restage / epi overlay
    }

    // ---- epilogue: O*inv -> LDS fp32 [64][68]; readback * gate -> fp16 ----
#pragma unroll
    for (int jd = 0; jd < 4; ++jd) {
        const int dcol = jd * 16 + frow;
#pragma unroll
        for (int v = 0; v < 4; ++v) {
            const int rn = wv * 16 + grp * 4 + v;
            Oe[rn * 68 + dcol] = oacc[jd][v] * inv[v];
        }
    }
    __syncthreads();
    {
        const int r   = tid >> 2;
        const int seg = tid & 3;
        const int n   = t * 64 + r;
        const int cg0 = h * 64 + seg * 16;
        const float* orow = &Oe[r * 68 + seg * 16];
        f32x4 o0 = *(const f32x4*)&orow[0];
        f32x4 o1 = *(const f32x4*)&orow[4];
        f32x4 o2 = *(const f32x4*)&orow[8];
        f32x4 o3 = *(const f32x4*)&orow[12];
        const f16x8 g0 = *(const f16x8*)&gh[(size_t)n * HD_ + cg0];
        const f16x8 g1 = *(const f16x8*)&gh[(size_t)n * HD_ + cg0 + 8];
        f16x8 r0, r1;
#pragma unroll
        for (int e = 0; e < 4; ++e) {
            r0[e]     = (_Float16)(o0[e] * (float)g0[e]);
            r0[4 + e] = (_Float16)(o1[e] * (float)g0[4 + e]);
            r1[e]     = (_Float16)(o2[e] * (float)g1[e]);
            r1[4 + e] = (_Float16)(o3[e] * (float)g1[4 + e]);
        }
        *(f16x8*)&of[(size_t)n * HD_ + cg0]     = r0;
        *(f16x8*)&of[(size_t)n * HD_ + cg0 + 8] = r1;
    }
}

// ---------------------------------------------------------------------------
// Kernel 3: out = (o*g)[4096x1024] @ Wo[1024x256], plain fp16 MFMA (R9:
// was split-bf16 -> 3x fewer MFMA, 2x fewer staged bytes). Tile 64x64,
// BK=64, XOR-8 swizzle, XCD swizzle.
// ---------------------------------------------------------------------------
__global__ __launch_bounds__(256) void out_mfma(
    const _Float16* __restrict__ of, const _Float16* __restrict__ WoTf,
    float* __restrict__ out)
{
    __shared__ __align__(16) _Float16 smem[2 * 4096];  // As, Bs [64][64] swz 8KB each
    _Float16* As = smem;
    _Float16* Bs = smem + 4096;

    const int lb  = blockIdx.x;
    const int xcd = lb & 7;
    const int idx = lb >> 3;
    const int rowg = (idx >> 2) * 8 + xcd;
    const int m0  = rowg * 64;
    const int c0  = (idx & 3) * 64;

    const int tid  = threadIdx.x;
    const int wave = tid >> 6;
    const int lane = tid & 63;
    const int wr   = wave >> 1;
    const int wc   = wave & 1;
    const int frow = lane & 15;
    const int grp  = lane >> 4;

    f32x4 acc[2][2];
#pragma unroll
    for (int i = 0; i < 2; ++i)
#pragma unroll
        for (int j = 0; j < 2; ++j) acc[i][j] = (f32x4){0.f, 0.f, 0.f, 0.f};

    for (int kt = 0; kt < 1024; kt += 64) {
        __syncthreads();
#pragma unroll
        for (int p = 0; p < 2; ++p) {
            const int lin = p * 4096 + tid * 16;
            const int row = lin >> 7;            // 0..63
            const int ch  = (lin >> 4) & 7;
            const int koff = kt + ((ch ^ (row & 7)) << 3);
            gload16(of   + (size_t)(m0 + row) * HD_ + koff, (char*)As + lin);
            gload16(WoTf + (size_t)(c0 + row) * HD_ + koff, (char*)Bs + lin);
        }
        __syncthreads();

#pragma unroll
        for (int ks = 0; ks < 2; ++ks) {
            f16x8 af[2], bf[2];
#pragma unroll
            for (int f = 0; f < 2; ++f) {
                const int ra = wr * 32 + f * 16 + frow;
                const int rb = wc * 32 + f * 16 + frow;
                af[f] = *(const f16x8*)((char*)As + ra * 128 + (((ks * 4 + grp) ^ (ra & 7)) << 4));
                bf[f] = *(const f16x8*)((char*)Bs + rb * 128 + (((ks * 4 + grp) ^ (rb & 7)) << 4));
            }
#pragma unroll
            for (int i = 0; i < 2; ++i)
#pragma unroll
                for (int j = 0; j < 2; ++j)
                    acc[i][j] = __builtin_amdgcn_mfma_f32_16x16x32_f16(af[i], bf[j], acc[i][j], 0, 0, 0);
        }
    }

    const int rbase = grp * 4;
#pragma unroll
    for (int i = 0; i < 2; ++i)
#pragma unroll
        for (int j = 0; j < 2; ++j) {
            const int c = c0 + wc * 32 + j * 16 + frow;
#pragma unroll
            for (int v = 0; v < 4; ++v) {
                const int n = m0 + wr * 32 + i * 16 + rbase + v;
                out[(size_t)n * C_ + c] = acc[i][j][v];
            }
        }
}

// ---------------------------------------------------------------------------
extern "C" void kernel_launch(void* const* d_in, const int* in_sizes, int n_in,
                              void* d_out, int out_size, void* d_ws, size_t ws_size,
                              hipStream_t stream)
{
    const float* q_x  = (const float*)d_in[0];
    const float* kv_x = (const float*)d_in[1];
    const float* bias = (const float*)d_in[2];
    const float* Wq   = (const float*)d_in[3];
    const float* Wk   = (const float*)d_in[4];
    const float* Wv   = (const float*)d_in[5];
    const float* Wg   = (const float*)d_in[6];
    const float* Wo   = (const float*)d_in[7];
    float* out = (float*)d_out;

    char* ws = (char*)d_ws;
    const size_t MB = 1048576;
    _Float16* qh   = (_Float16*)(ws);             // [16][4096][64] fp16, pre-scaled 1/8
    _Float16* kh   = (_Float16*)(ws + 8  * MB);
    _Float16* vh   = (_Float16*)(ws + 16 * MB);
    _Float16* gh   = (_Float16*)(ws + 24 * MB);   // [4096][1024] fp16 sigmoid gate
    _Float16* of   = (_Float16*)(ws + 32 * MB);   // [4096][1024] fp16 gated attn out
    _Float16* Xf   = (_Float16*)(ws + 40 * MB);   // [2][4096][256] fp16
    _Float16* WTf  = (_Float16*)(ws + 44 * MB);   // [4][1024][256] fp16
    _Float16* WoTf = (_Float16*)(ws + 46 * MB);   // [256][1024] fp16

    convert_kernel<<<832, 256, 0, stream>>>(q_x, kv_x, Wq, Wk, Wv, Wg, Wo,
                                            Xf, WTf, WoTf);
    proj_mfma<<<1024, 256, 0, stream>>>(Xf, WTf, qh, kh, vh, gh);
    attn_mfma<<<1024, 256, 0, stream>>>(qh, kh, vh, bias, gh, of);
    out_mfma<<<256, 256, 0, stream>>>(of, WoTf, out);
}

// Round 10
// 159.685 us; speedup vs baseline: 1.0857x; 1.0249x over previous
//
#include <hip/hip_runtime.h>

#define N_ 4096
#define C_ 256
#define H_ 16
#define D_ 64
#define HD_ 1024

typedef __attribute__((ext_vector_type(8))) _Float16 f16x8;
typedef __attribute__((ext_vector_type(4))) _Float16 f16x4;
typedef __attribute__((ext_vector_type(4))) float f32x4;

__device__ __forceinline__ void gload16(const void* g, void* l) {
    __builtin_amdgcn_global_load_lds(
        (const __attribute__((address_space(1))) unsigned int*)g,
        (__attribute__((address_space(3))) unsigned int*)l, 16, 0, 0);
}

// ---------------------------------------------------------------------------
// Kernel 0: convert fp32 inputs -> fp16 (X, Wq..Wg, Wo). W transposed
// K-contiguous. (unchanged from R9)
// ---------------------------------------------------------------------------
__global__ __launch_bounds__(256) void convert_kernel(
    const float* __restrict__ q_x, const float* __restrict__ kv_x,
    const float* __restrict__ Wq, const float* __restrict__ Wk,
    const float* __restrict__ Wv, const float* __restrict__ Wg,
    const float* __restrict__ Wo,
    _Float16* __restrict__ Xf, _Float16* __restrict__ WTf,
    _Float16* __restrict__ WoTf)
{
    __shared__ float ts[64][65];
    const int b = blockIdx.x;
    const int tid = threadIdx.x;

    if (b < 512) {
        const int seg = b >> 8;
        const float* src = seg ? kv_x : q_x;
        _Float16* df = Xf + (size_t)seg * 1048576;
        const int base = (b & 255) * 4096 + tid * 16;
#pragma unroll
        for (int q = 0; q < 4; ++q) {
            float4 v = *(const float4*)&src[base + q * 4];
            f16x4 fv;
            fv[0] = (_Float16)v.x; fv[1] = (_Float16)v.y;
            fv[2] = (_Float16)v.z; fv[3] = (_Float16)v.w;
            *(f16x4*)&df[base + q * 4] = fv;
        }
        return;
    }

    const float* src;
    _Float16* df;
    int srcC, dstC, r0, c0;
    if (b < 768) {
        const int widx = (b - 512) >> 6;
        const int tile = (b - 512) & 63;
        src = (widx == 0) ? Wq : (widx == 1) ? Wk : (widx == 2) ? Wv : Wg;
        df = WTf + (size_t)widx * 262144;
        srcC = 1024; dstC = 256;
        r0 = (tile >> 4) * 64;
        c0 = (tile & 15) * 64;
    } else {
        const int tile = b - 768;
        src = Wo; df = WoTf;
        srcC = 256; dstC = 1024;
        r0 = (tile >> 2) * 64;
        c0 = (tile & 3) * 64;
    }
    {
        const int r = tid >> 2;
        const int cch = (tid & 3) * 16;
#pragma unroll
        for (int q = 0; q < 4; ++q) {
            float4 v = *(const float4*)&src[(size_t)(r0 + r) * srcC + c0 + cch + q * 4];
            ts[r][cch + q * 4 + 0] = v.x;
            ts[r][cch + q * 4 + 1] = v.y;
            ts[r][cch + q * 4 + 2] = v.z;
            ts[r][cch + q * 4 + 3] = v.w;
        }
    }
    __syncthreads();
    {
        const int c = tid >> 2;
        const int rch = (tid & 3) * 16;
#pragma unroll
        for (int q = 0; q < 4; ++q) {
            f16x4 fv;
#pragma unroll
            for (int j = 0; j < 4; ++j)
                fv[j] = (_Float16)ts[rch + q * 4 + j][c];
            *(f16x4*)&df[(size_t)(c0 + c) * dstC + r0 + rch + q * 4] = fv;
        }
    }
}

// ---------------------------------------------------------------------------
// Kernel 1: projections via fp16 MFMA. 128x128 tile, BK=64, XOR-8 swizzle,
// XCD swizzle, LDS-routed vectorized epilogue. (unchanged from R9)
// ---------------------------------------------------------------------------
__global__ __launch_bounds__(256) void proj_mfma(
    const _Float16* __restrict__ Xf, const _Float16* __restrict__ WTf,
    _Float16* __restrict__ qh, _Float16* __restrict__ kh,
    _Float16* __restrict__ vh, _Float16* __restrict__ gh)
{
    __shared__ __align__(16) char psmem[34816];
    _Float16* As = (_Float16*)psmem;
    _Float16* Bs = (_Float16*)(psmem + 16384);

    const int lb  = blockIdx.x;
    const int xcd = lb & 7;
    const int gr  = (lb >> 6) * 8 + xcd;    // 0..127 -> (g, row-tile)
    const int g   = gr >> 5;
    const int m0  = (gr & 31) * 128;
    const int c0  = ((lb >> 3) & 7) * 128;

    const _Float16* A = Xf + ((g == 1 || g == 2) ? 1048576 : 0);
    const _Float16* B = WTf + (size_t)g * 262144;

    const int tid  = threadIdx.x;
    const int wave = tid >> 6;
    const int lane = tid & 63;
    const int wr   = wave >> 1;
    const int wc   = wave & 1;
    const int frow = lane & 15;
    const int grp  = lane >> 4;

    f32x4 acc[4][4];
#pragma unroll
    for (int i = 0; i < 4; ++i)
#pragma unroll
        for (int j = 0; j < 4; ++j) acc[i][j] = (f32x4){0.f, 0.f, 0.f, 0.f};

    const int srow = tid >> 3;
    const int sch  = tid & 7;

    for (int kt = 0; kt < 256; kt += 64) {
        __syncthreads();
#pragma unroll
        for (int p = 0; p < 4; ++p) {
            const int row = p * 32 + srow;
            const int koff = kt + ((sch ^ (row & 7)) << 3);
            gload16(A + (size_t)(m0 + row) * 256 + koff, (char*)As + p * 4096 + tid * 16);
            gload16(B + (size_t)(c0 + row) * 256 + koff, (char*)Bs + p * 4096 + tid * 16);
        }
        __syncthreads();

#pragma unroll
        for (int ks = 0; ks < 2; ++ks) {
            f16x8 af[4], bf[4];
#pragma unroll
            for (int f = 0; f < 4; ++f) {
                const int ra = wr * 64 + f * 16 + frow;
                const int rb = wc * 64 + f * 16 + frow;
                af[f] = *(const f16x8*)((char*)As + ra * 128 + (((ks * 4 + grp) ^ (ra & 7)) << 4));
                bf[f] = *(const f16x8*)((char*)Bs + rb * 128 + (((ks * 4 + grp) ^ (rb & 7)) << 4));
            }
#pragma unroll
            for (int i = 0; i < 4; ++i)
#pragma unroll
                for (int j = 0; j < 4; ++j)
                    acc[i][j] = __builtin_amdgcn_mfma_f32_16x16x32_f16(af[i], bf[j], acc[i][j], 0, 0, 0);
        }
    }

    __syncthreads();
    _Float16* Epi = (_Float16*)psmem;        // [128][136] fp16
    {
        const float scale = (g == 0) ? 0.125f : 1.f;
#pragma unroll
        for (int i = 0; i < 4; ++i)
#pragma unroll
            for (int j = 0; j < 4; ++j) {
                const int rr = wr * 64 + i * 16 + grp * 4;
                const int cc = wc * 64 + j * 16 + frow;
#pragma unroll
                for (int v = 0; v < 4; ++v) {
                    float x = acc[i][j][v];
                    x = (g == 3) ? 1.f / (1.f + __expf(-x)) : x * scale;
                    Epi[(rr + v) * 136 + cc] = (_Float16)x;
                }
            }
    }
    __syncthreads();
    {
        const int ch   = tid & 15;
        const int head = ch >> 3;
        const int e8   = (ch & 7) * 8;
#pragma unroll
        for (int p = 0; p < 8; ++p) {
            const int r = p * 16 + (tid >> 4);
            const f16x8 val = *(const f16x8*)&Epi[r * 136 + head * 64 + e8];
            if (g == 3) {
                *(f16x8*)&gh[(size_t)(m0 + r) * HD_ + c0 + head * 64 + e8] = val;
            } else {
                _Float16* dst = (g == 0) ? qh : (g == 1) ? kh : vh;
                const int hh = (c0 >> 6) + head;
                *(f16x8*)&dst[((size_t)hh * N_ + m0 + r) * D_ + e8] = val;
            }
        }
    }
}

// ---------------------------------------------------------------------------
// Kernel 2: local attention via fp16 MFMA. One block per (h,t), 4 waves.
// XCD swizzle. R10: SINGLE K-stage (256 slots x 64 d, 32 KB) -> QK phase
// drops from 4 barrier drains to 2, and all 10 staging gloads issue
// back-to-back. LDS 40 KB -> still 4 blocks/CU.
// ---------------------------------------------------------------------------
__global__ __launch_bounds__(256, 4) void attn_mfma(
    const _Float16* __restrict__ qh, const _Float16* __restrict__ kh,
    const _Float16* __restrict__ vh, const float* __restrict__ bias,
    const _Float16* __restrict__ gh, _Float16* __restrict__ of)
{
    __shared__ __align__(16) char smem[40960];
    _Float16* Qs = (_Float16*)smem;              // phase A: [64][64] swz, 8 KB
    char* Ks = smem + 8192;                      // phase A: [256][64] swz, 32 KB
    _Float16* Ps = (_Float16*)smem;              // phase B: [64][136], 17408 B
    _Float16* Vs = (_Float16*)(smem + 17408);    // phase B: [64][136], 17408 B
    float* Oe = (float*)smem;                    // epi: [64][68] fp32

    const int lb  = blockIdx.x;
    const int xcd = lb & 7;
    const int j_  = lb >> 3;
    const int h   = j_ >> 3;
    const int t   = xcd * 8 + (j_ & 7);
    const int tid = threadIdx.x;
    const int lane = tid & 63;
    const int wv = tid >> 6;
    const int frow = lane & 15;
    const int grp = lane >> 4;
    const int kbase = t * 64 - 96;

    const char* qbase = (const char*)qh + (size_t)(h * N_ + t * 64) * 128;
    const char* kbase_p = (const char*)kh + (size_t)h * N_ * 128;

    // ---- stage Q (8 KB) + K (32 KB, all 256 slots), async back-to-back ----
#pragma unroll
    for (int q = 0; q < 2; ++q) {
        const int lin = q * 4096 + tid * 16;
        const int row = lin >> 7;
        const int ch = (lin >> 4) & 7;
        gload16(qbase + row * 128 + ((ch ^ (row & 7)) << 4), (char*)Qs + lin);
    }
#pragma unroll
    for (int q = 0; q < 8; ++q) {
        const int lin = q * 4096 + tid * 16;
        const int row = lin >> 7;              // 0..255
        const int ch = (lin >> 4) & 7;
        const int kg = kbase + row;
        if ((unsigned)kg < (unsigned)N_) {
            gload16(kbase_p + (size_t)kg * 128 + ((ch ^ (row & 7)) << 4), Ks + lin);
        } else {
            *(float4*)(Ks + lin) = make_float4(0.f, 0.f, 0.f, 0.f);
        }
    }

    // ---- bias -> accumulator init (all 256 slots) ----
    f32x4 sacc[16];
    {
        const int rowg = t * 64 + wv * 16 + grp * 4;
#pragma unroll
        for (int j = 0; j < 16; ++j) {
            const int colg = kbase + j * 16 + frow;
            const bool ok = (unsigned)colg < (unsigned)N_;
#pragma unroll
            for (int v = 0; v < 4; ++v)
                sacc[j][v] = ok ? bias[(size_t)(rowg + v) * N_ + colg] : 0.f;
        }
    }
    __syncthreads();   // Q+K staged

    // ---- QK: 32 MFMAs, one barrier ----
    {
        const int rq = wv * 16 + frow;
#pragma unroll
        for (int ks = 0; ks < 2; ++ks) {
            const f16x8 aq = *(const f16x8*)((char*)Qs + rq * 128 + (((ks * 4 + grp) ^ (rq & 7)) << 4));
#pragma unroll
            for (int j = 0; j < 16; ++j) {
                const int rk = j * 16 + frow;     // slot 0..255
                const f16x8 bk = *(const f16x8*)(Ks + rk * 128 + (((ks * 4 + grp) ^ (rk & 7)) << 4));
                sacc[j] = __builtin_amdgcn_mfma_f32_16x16x32_f16(aq, bk, sacc[j], 0, 0, 0);
            }
        }
    }
    __syncthreads();   // Q/K dead; phase B may overlay

    // ---- softmax over 256 slots/row (sacc[j] holds slot j*16+frow) ----
    float inv[4];
#pragma unroll
    for (int v = 0; v < 4; ++v) {
        float m = sacc[0][v];
#pragma unroll
        for (int f = 1; f < 16; ++f) m = fmaxf(m, sacc[f][v]);
        m = fmaxf(m, __shfl_xor(m, 1));
        m = fmaxf(m, __shfl_xor(m, 2));
        m = fmaxf(m, __shfl_xor(m, 4));
        m = fmaxf(m, __shfl_xor(m, 8));
        float l = 0.f;
#pragma unroll
        for (int f = 0; f < 16; ++f) {
            float e = __expf(sacc[f][v] - m);
            sacc[f][v] = e;
            l += e;
        }
        l += __shfl_xor(l, 1);
        l += __shfl_xor(l, 2);
        l += __shfl_xor(l, 4);
        l += __shfl_xor(l, 8);
        inv[v] = 1.f / l;
    }

    // ---- PV over 2 slot-chunks of 128; P written per-chunk from sacc ----
    f32x4 oacc[4];
#pragma unroll
    for (int jd = 0; jd < 4; ++jd) oacc[jd] = (f32x4){0.f, 0.f, 0.f, 0.f};

#pragma unroll
    for (int c = 0; c < 2; ++c) {
        // stage V^T chunk: Vs[d][sl], sl 0..127
        {
            const int sl = tid >> 1;
            const int d0 = (tid & 1) * 32;
            const int kg = kbase + c * 128 + sl;
            f16x8 vv[4];
            if ((unsigned)kg < (unsigned)N_) {
                const f16x8* vp = (const f16x8*)(vh + ((size_t)h * N_ + kg) * D_ + d0);
#pragma unroll
                for (int q = 0; q < 4; ++q) vv[q] = vp[q];
            } else {
#pragma unroll
                for (int q = 0; q < 4; ++q)
#pragma unroll
                    for (int e = 0; e < 8; ++e) vv[q][e] = (_Float16)0.f;
            }
#pragma unroll
            for (int q = 0; q < 4; ++q)
#pragma unroll
                for (int e = 0; e < 8; ++e)
                    Vs[(d0 + q * 8 + e) * 136 + sl] = vv[q][e];
        }
        // write this chunk's unnormalized P (sacc[c*8+j] = slot c*128+j*16+frow)
        {
            const int rb = wv * 16 + grp * 4;
#pragma unroll
            for (int j = 0; j < 8; ++j) {
                const int col = j * 16 + frow;
#pragma unroll
                for (int v = 0; v < 4; ++v)
                    Ps[(rb + v) * 136 + col] = (_Float16)sacc[c * 8 + j][v];
            }
        }
        __syncthreads();   // Ps + Vs ready
        const int rp = wv * 16 + frow;
#pragma unroll
        for (int ks = 0; ks < 4; ++ks) {
            const f16x8 ap = *(const f16x8*)((char*)Ps + rp * 272 + ks * 64 + grp * 16);
#pragma unroll
            for (int jd = 0; jd < 4; ++jd) {
                const f16x8 bv = *(const f16x8*)((char*)Vs + (jd * 16 + frow) * 272 + ks * 64 + grp * 16);
                oacc[jd] = __builtin_amdgcn_mfma_f32_16x16x32_f16(ap, bv, oacc[jd], 0, 0, 0);
            }
        }
        __syncthreads();   // Ps/Vs reads done before restage / epi overlay
    }

    // ---- epilogue: O*inv -> LDS fp32 [64][68]; readback * gate -> fp16 ----
#pragma unroll
    for (int jd = 0; jd < 4; ++jd) {
        const int dcol = jd * 16 + frow;
#pragma unroll
        for (int v = 0; v < 4; ++v) {
            const int rn = wv * 16 + grp * 4 + v;
            Oe[rn * 68 + dcol] = oacc[jd][v] * inv[v];
        }
    }
    __syncthreads();
    {
        const int r   = tid >> 2;
        const int seg = tid & 3;
        const int n   = t * 64 + r;
        const int cg0 = h * 64 + seg * 16;
        const float* orow = &Oe[r * 68 + seg * 16];
        f32x4 o0 = *(const f32x4*)&orow[0];
        f32x4 o1 = *(const f32x4*)&orow[4];
        f32x4 o2 = *(const f32x4*)&orow[8];
        f32x4 o3 = *(const f32x4*)&orow[12];
        const f16x8 g0 = *(const f16x8*)&gh[(size_t)n * HD_ + cg0];
        const f16x8 g1 = *(const f16x8*)&gh[(size_t)n * HD_ + cg0 + 8];
        f16x8 r0, r1;
#pragma unroll
        for (int e = 0; e < 4; ++e) {
            r0[e]     = (_Float16)(o0[e] * (float)g0[e]);
            r0[4 + e] = (_Float16)(o1[e] * (float)g0[4 + e]);
            r1[e]     = (_Float16)(o2[e] * (float)g1[e]);
            r1[4 + e] = (_Float16)(o3[e] * (float)g1[4 + e]);
        }
        *(f16x8*)&of[(size_t)n * HD_ + cg0]     = r0;
        *(f16x8*)&of[(size_t)n * HD_ + cg0 + 8] = r1;
    }
}

// ---------------------------------------------------------------------------
// Kernel 3: out = (o*g)[4096x1024] @ Wo[1024x256], fp16 MFMA. R10: 32x64
// tiles -> 512 blocks = 2 blocks/CU (was 64x64 -> 256 = 1/CU with fully
// exposed barrier drains). BK=64, XOR-8 swizzle, XCD swizzle.
// ---------------------------------------------------------------------------
__global__ __launch_bounds__(256) void out_mfma(
    const _Float16* __restrict__ of, const _Float16* __restrict__ WoTf,
    float* __restrict__ out)
{
    __shared__ __align__(16) _Float16 smem[2048 + 4096];  // As [32][64] 4KB, Bs [64][64] 8KB
    _Float16* As = smem;
    _Float16* Bs = smem + 2048;

    const int lb  = blockIdx.x;
    const int xcd = lb & 7;
    const int s   = lb >> 3;                 // 0..63
    const int rowt = (s >> 2) * 8 + xcd;     // 0..127
    const int m0  = rowt * 32;
    const int c0  = (s & 3) * 64;

    const int tid  = threadIdx.x;
    const int wave = tid >> 6;
    const int lane = tid & 63;
    const int wr   = wave >> 1;
    const int wc   = wave & 1;
    const int frow = lane & 15;
    const int grp  = lane >> 4;

    f32x4 acc[2];
#pragma unroll
    for (int j = 0; j < 2; ++j) acc[j] = (f32x4){0.f, 0.f, 0.f, 0.f};

    for (int kt = 0; kt < 1024; kt += 64) {
        __syncthreads();
        {   // A: 32 rows x 64 k = 4 KB = 1 chunk/thread
            const int row = tid >> 3;            // 0..31
            const int ch  = tid & 7;
            const int koff = kt + ((ch ^ (row & 7)) << 3);
            gload16(of + (size_t)(m0 + row) * HD_ + koff, (char*)As + tid * 16);
        }
#pragma unroll
        for (int p = 0; p < 2; ++p) {            // B: 64 rows x 64 k = 8 KB
            const int lin = p * 4096 + tid * 16;
            const int row = lin >> 7;            // 0..63
            const int ch  = (lin >> 4) & 7;
            const int koff = kt + ((ch ^ (row & 7)) << 3);
            gload16(WoTf + (size_t)(c0 + row) * HD_ + koff, (char*)Bs + lin);
        }
        __syncthreads();

#pragma unroll
        for (int ks = 0; ks < 2; ++ks) {
            const int ra = wr * 16 + frow;
            const f16x8 af = *(const f16x8*)((char*)As + ra * 128 + (((ks * 4 + grp) ^ (ra & 7)) << 4));
#pragma unroll
            for (int j = 0; j < 2; ++j) {
                const int rb = wc * 32 + j * 16 + frow;
                const f16x8 bf = *(const f16x8*)((char*)Bs + rb * 128 + (((ks * 4 + grp) ^ (rb & 7)) << 4));
                acc[j] = __builtin_amdgcn_mfma_f32_16x16x32_f16(af, bf, acc[j], 0, 0, 0);
            }
        }
    }

    const int rbase = grp * 4;
#pragma unroll
    for (int j = 0; j < 2; ++j) {
        const int c = c0 + wc * 32 + j * 16 + frow;
#pragma unroll
        for (int v = 0; v < 4; ++v) {
            const int n = m0 + wr * 16 + rbase + v;
            out[(size_t)n * C_ + c] = acc[j][v];
        }
    }
}

// ---------------------------------------------------------------------------
extern "C" void kernel_launch(void* const* d_in, const int* in_sizes, int n_in,
                              void* d_out, int out_size, void* d_ws, size_t ws_size,
                              hipStream_t stream)
{
    const float* q_x  = (const float*)d_in[0];
    const float* kv_x = (const float*)d_in[1];
    const float* bias = (const float*)d_in[2];
    const float* Wq   = (const float*)d_in[3];
    const float* Wk   = (const float*)d_in[4];
    const float* Wv   = (const float*)d_in[5];
    const float* Wg   = (const float*)d_in[6];
    const float* Wo   = (const float*)d_in[7];
    float* out = (float*)d_out;

    char* ws = (char*)d_ws;
    const size_t MB = 1048576;
    _Float16* qh   = (_Float16*)(ws);             // [16][4096][64] fp16, pre-scaled 1/8
    _Float16* kh   = (_Float16*)(ws + 8  * MB);
    _Float16* vh   = (_Float16*)(ws + 16 * MB);
    _Float16* gh   = (_Float16*)(ws + 24 * MB);   // [4096][1024] fp16 sigmoid gate
    _Float16* of   = (_Float16*)(ws + 32 * MB);   // [4096][1024] fp16 gated attn out
    _Float16* Xf   = (_Float16*)(ws + 40 * MB);   // [2][4096][256] fp16
    _Float16* WTf  = (_Float16*)(ws + 44 * MB);   // [4][1024][256] fp16
    _Float16* WoTf = (_Float16*)(ws + 46 * MB);   // [256][1024] fp16

    convert_kernel<<<832, 256, 0, stream>>>(q_x, kv_x, Wq, Wk, Wv, Wg, Wo,
                                            Xf, WTf, WoTf);
    proj_mfma<<<1024, 256, 0, stream>>>(Xf, WTf, qh, kh, vh, gh);
    attn_mfma<<<1024, 256, 0, stream>>>(qh, kh, vh, bias, gh, of);
    out_mfma<<<512, 256, 0, stream>>>(of, WoTf, out);
}